// Round 12
// baseline (13265.787 us; speedup 1.0000x reference)
//
#include <hip/hip_runtime.h>
#include <cmath>

#define TT 512
#define BB 64
#define HH 512
#define II 128
#define NBLK 256

typedef float v2f __attribute__((ext_vector_type(2)));
__device__ __forceinline__ v2f fma2(v2f a, v2f b, v2f c) { return __builtin_elementwise_fma(a, b, c); }

// dynamic LDS floats: wlds 16*1024 =16384 | part 16*16*64 =16384 |
// gates 16*64 =1024 | cst 256 | bsum 16   => ~133 KB  (=> 1 block/CU max)
#define SMEM_FLOATS (16384 + 16384 + 1024 + 256 + 16)
#define SMEM_BYTES  (SMEM_FLOATS * 4)

__device__ __forceinline__ float sigm(float v) { return 1.0f / (1.0f + expf(-v)); }
__device__ __forceinline__ unsigned umin2(unsigned a, unsigned b) { return a < b ? a : b; }
#define CBAR() asm volatile("" ::: "memory")   // compiler-only reorder fence

// One k-slice: 16 weights (rows 0..15) from LDS (wave-uniform broadcast),
// 8 v_pk_fma_f32. acc[j] covers rows (2j, 2j+1).
__device__ __forceinline__ void step(const float* wk, float v, v2f (&acc)[8]) {
  const float4* wp = (const float4*)wk;
  const float4 w0 = wp[0], w1 = wp[1], w2 = wp[2], w3 = wp[3];
  const v2f vb = (v2f){v, v};
  acc[0] = fma2((v2f){w0.x, w0.y}, vb, acc[0]);
  acc[1] = fma2((v2f){w0.z, w0.w}, vb, acc[1]);
  acc[2] = fma2((v2f){w1.x, w1.y}, vb, acc[2]);
  acc[3] = fma2((v2f){w1.z, w1.w}, vb, acc[3]);
  acc[4] = fma2((v2f){w2.x, w2.y}, vb, acc[4]);
  acc[5] = fma2((v2f){w2.z, w2.w}, vb, acc[5]);
  acc[6] = fma2((v2f){w3.x, w3.y}, vb, acc[6]);
  acc[7] = fma2((v2f){w3.z, w3.w}, vb, acc[7]);
}

// Batch-load KN h values via relaxed AGENT-scope atomic loads (sc0 sc1 —
// served from the coherence point; immune to stale local cache lines).
// Compiler-managed waitcnts: sound under any spilling. Fully unrolled ->
// all KN loads in flight together (one latency exposure).
template<int KN>
__device__ __forceinline__ void loadva(const float* __restrict__ src, int k0,
                                       int b, float (&v)[KN]) {
#pragma unroll
  for (int i = 0; i < KN; ++i)
    v[i] = __hip_atomic_load(src + (size_t)(k0 + i) * BB + b,
                             __ATOMIC_RELAXED, __HIP_MEMORY_SCOPE_AGENT);
}
// Plain cached batch load (x only — immutable, L2-resident across phases).
template<int KN>
__device__ __forceinline__ void loadv(const float* __restrict__ src, int k0,
                                      int b, float (&v)[KN]) {
#pragma unroll
  for (int i = 0; i < KN; ++i) v[i] = src[(size_t)(k0 + i) * BB + b];
}
template<int KN>
__device__ __forceinline__ void consume(const float* __restrict__ wbase, int k0,
                                        const float (&v)[KN], v2f (&acc)[8]) {
#pragma unroll
  for (int i = 0; i < KN; ++i) step(wbase + (size_t)(k0 + i) * 16, v[i], acc);
}

// ---------------------------------------------------------------------------
// Transpose x: [64][512][128] (b,t,k) -> xT: [512][128][64] (t,k,b)
// ---------------------------------------------------------------------------
__global__ __launch_bounds__(1024) void k_transpose_x(const float* __restrict__ x,
                                                      float* __restrict__ xT) {
  __shared__ float tile[64][65];
  const int t  = blockIdx.x >> 1;
  const int k0 = (blockIdx.x & 1) << 6;
  const int lk = threadIdx.x & 63;
  const int lb = threadIdx.x >> 6;
#pragma unroll
  for (int bp = 0; bp < 64; bp += 16) {
    const int b = bp + lb;
    tile[lk][b] = x[((size_t)b * TT + t) * II + k0 + lk];
  }
  __syncthreads();
  const int b2  = threadIdx.x & 63;
  const int kk0 = threadIdx.x >> 6;
#pragma unroll
  for (int kp = 0; kp < 64; kp += 16) {
    const int kk = kp + kk0;
    xT[((size_t)t * II + k0 + kk) * BB + b2] = tile[kk][b2];
  }
}

__global__ void k_init_flags(unsigned* flags) { flags[threadIdx.x] = 0u; }

// ---------------------------------------------------------------------------
// Persistent pipelined 2-layer LSTM.
// PRODUCER (proven, rounds 3/10/11): agent atomic h stores (write-through) ->
//   __syncthreads (drains vmcnt) -> tid0 __threadfence (release) -> flag.
// CONSUMER (delta vs round 11): NO acquire fence/inv. h read via relaxed
//   agent atomic loads (coherence-point reads). x stays plain-cached and now
//   survives in L2 across phases (the old inv wiped it every phase).
// REGISTERS (delta): __launch_bounds__(1024,4) -> 128-VGPR budget matching
//   the real 1-block/CU occupancy (LDS-capped), so the 32-deep load batches
//   stay in registers (round 11 spilled them at the default 64-VGPR target).
// Thread map: tid = kseg(4b) | b(6b); each thread: all 16 rows, K/16 k's.
// ---------------------------------------------------------------------------
__global__ __launch_bounds__(1024, 4) void k_lstm_persist(
    const float* __restrict__ xT,
    const float* __restrict__ W_ih0, const float* __restrict__ W_hh0,
    const float* __restrict__ b_ih0, const float* __restrict__ b_hh0,
    const float* __restrict__ W_ih1, const float* __restrict__ W_hh1,
    const float* __restrict__ b_ih1, const float* __restrict__ b_hh1,
    float* __restrict__ h0ring, float* __restrict__ h1ring,
    unsigned* __restrict__ flags)
{
  extern __shared__ float smem[];
  float* wlds  = smem;            // [k up to 1024][16 rows] k-major
  float* part  = wlds + 16384;    // [row16][kseg16][b64]
  float* gates = part + 16384;    // [row16][b64]
  float* cst   = gates + 1024;    // [u4][b64]
  float* bsum  = cst + 256;       // [16]

  const int bid = blockIdx.x;
  const int L   = bid >> 7;
  const int ub  = (bid & 127) << 2;   // 4 hidden units per block
  const int tid = threadIdx.x;

  const float* WA = L ? W_ih1 : W_ih0;
  const float* WB = L ? W_hh1 : W_hh0;
  const int KA = L ? HH : II;

  // ---- one-time: stage weights k-major + bias sums + c=0 ----
  const int ktot = KA + HH;
  for (int idx = tid; idx < 16 * ktot; idx += 1024) {
    const int k  = idx >> 4;
    const int lr = idx & 15;
    const int u = lr >> 2, q = lr & 3;
    const int G = q * HH + ub + u;           // i,f,g,o chunk order
    wlds[idx] = (k < KA) ? WA[G * KA + k] : WB[G * HH + (k - KA)];
  }
  if (tid < 16) {
    const int u = tid >> 2, q = tid & 3;
    const int G = q * HH + ub + u;
    bsum[tid] = L ? (b_ih1[G] + b_hh1[G]) : (b_ih0[G] + b_hh0[G]);
  }
  if (tid < 256) cst[tid] = 0.0f;
  __syncthreads();

  const int kseg = tid >> 6;   // 0..15
  const int b    = tid & 63;

  for (int s = 0; s <= TT; ++s) {
    const int t = L ? (s - 1) : s;
    const bool active = (t >= 0 && t < TT);
    const bool first  = (t == 0);

    v2f acc[8];
#pragma unroll
    for (int j = 0; j < 8; ++j) acc[j] = (v2f){0.0f, 0.0f};

    // ---- L0 x loads BEFORE the wait (immutable; complete during spin) ----
    float xv[8];
    if (active && L == 0) {
      loadv<8>(xT + (size_t)t * (II * BB), kseg * 8, b, xv);
    }

    // ---- wait: all blocks published phase s-1 (NO inv afterwards) ----
    if (s > 0) {
      if (tid < 64) {
        const unsigned tgt = (unsigned)s;
        for (;;) {
          const unsigned m0 = __hip_atomic_load(flags + tid,       __ATOMIC_RELAXED, __HIP_MEMORY_SCOPE_AGENT);
          const unsigned m1 = __hip_atomic_load(flags + tid +  64, __ATOMIC_RELAXED, __HIP_MEMORY_SCOPE_AGENT);
          const unsigned m2 = __hip_atomic_load(flags + tid + 128, __ATOMIC_RELAXED, __HIP_MEMORY_SCOPE_AGENT);
          const unsigned m3 = __hip_atomic_load(flags + tid + 192, __ATOMIC_RELAXED, __HIP_MEMORY_SCOPE_AGENT);
          const unsigned mn = umin2(umin2(m0, m1), umin2(m2, m3));
          if (__all(mn >= tgt)) break;
          __builtin_amdgcn_s_sleep(1);
        }
      }
      __syncthreads();
      CBAR();   // keep h loads below the spin at IR level
    }

    if (active) {
      if (L == 0) {
        consume<8>(wlds, kseg * 8, xv, acc);
        if (!first) {  // B-part: h0[s-1] @ parity (s-1)&1 — 32-deep MLP
          float hv[32];
          loadva<32>(h0ring + (size_t)((s - 1) & 1) * (HH * BB), kseg * 32, b, hv);
          consume<32>(wlds + (size_t)II * 16, kseg * 32, hv, acc);
        }
      } else {
        const float* h0p = h0ring + (size_t)((s - 1) & 1) * (HH * BB);
        if (first) {
          float av[32];
          loadva<32>(h0p, kseg * 32, b, av);
          consume<32>(wlds, kseg * 32, av, acc);
        } else {
          // issue ALL 64 h loads before consuming either span
          float av[32], bv[32];
          loadva<32>(h0p, kseg * 32, b, av);
          loadva<32>(h1ring + (size_t)(s & 1) * (HH * BB), kseg * 32, b, bv);
          consume<32>(wlds, kseg * 32, av, acc);
          consume<32>(wlds + (size_t)HH * 16, kseg * 32, bv, acc);
        }
      }

      // ---- reduce 16 ksegs -> gates (lanes = b: conflict-free) ----
#pragma unroll
      for (int j = 0; j < 4; ++j) {
        part[(((j << 2) + 0) * 16 + kseg) * 64 + b] = acc[(j << 1)].x;
        part[(((j << 2) + 1) * 16 + kseg) * 64 + b] = acc[(j << 1)].y;
        part[(((j << 2) + 2) * 16 + kseg) * 64 + b] = acc[(j << 1) + 1].x;
        part[(((j << 2) + 3) * 16 + kseg) * 64 + b] = acc[(j << 1) + 1].y;
      }
      __syncthreads();
      {
        const int row = tid >> 6;
        const int bb  = tid & 63;
        float g = 0.0f;
#pragma unroll
        for (int ks = 0; ks < 16; ++ks) g += part[(row * 16 + ks) * 64 + bb];
        gates[row * 64 + bb] = g + bsum[row];
      }
      __syncthreads();

      if (tid < 256) {  // cell update; h via agent-scope write-through store
        const int u = tid >> 6, bb = tid & 63;
        const float gi = sigm(gates[((u << 2) + 0) * 64 + bb]);
        const float gf = sigm(gates[((u << 2) + 1) * 64 + bb]);
        const float gg = tanhf(gates[((u << 2) + 2) * 64 + bb]);
        const float go = sigm(gates[((u << 2) + 3) * 64 + bb]);
        const float cold = first ? 0.0f : cst[u * 64 + bb];
        const float cn = gf * cold + gi * gg;
        const float hn = go * tanhf(cn);
        cst[u * 64 + bb] = cn;
        float* hdst = (L ? h1ring : h0ring) + (size_t)(t & 1) * (HH * BB);
        __hip_atomic_store(hdst + (ub + u) * 64 + bb, hn,
                           __ATOMIC_RELAXED, __HIP_MEMORY_SCOPE_AGENT);
      }
    }

    // barrier drains each wave's stores; then proven release publish
    __syncthreads();
    if (tid == 0) {
      __threadfence();   // proven release (rounds 3/10/11); cheap: L2 clean
      __hip_atomic_store(flags + bid, (unsigned)(s + 1),
                         __ATOMIC_RELAXED, __HIP_MEMORY_SCOPE_AGENT);
    }
  }
}

// ---------------------------------------------------------------------------
// out[b] = sum_j h1_last[j][b] * Wl[j] + bl[0]
// ---------------------------------------------------------------------------
__global__ __launch_bounds__(512) void k_final(const float* __restrict__ h1last,
                                               const float* __restrict__ Wl,
                                               const float* __restrict__ bl,
                                               float* __restrict__ out) {
  __shared__ float red[8][64];
  const int jg = threadIdx.x >> 6, b = threadIdx.x & 63;
  float a = 0.0f;
  for (int jj = 0; jj < 64; ++jj) {
    const int j = (jg << 6) + jj;
    a += h1last[j * BB + b] * Wl[j];
  }
  red[jg][b] = a;
  __syncthreads();
  if (threadIdx.x < 64) {
    float s = bl[0];
#pragma unroll
    for (int g = 0; g < 8; ++g) s += red[g][threadIdx.x];
    out[threadIdx.x] = s;
  }
}

extern "C" void kernel_launch(void* const* d_in, const int* in_sizes, int n_in,
                              void* d_out, int out_size, void* d_ws, size_t ws_size,
                              hipStream_t stream) {
  (void)in_sizes; (void)n_in; (void)out_size; (void)ws_size;
  const float* x     = (const float*)d_in[0];
  const float* W_ih0 = (const float*)d_in[1];
  const float* W_hh0 = (const float*)d_in[2];
  const float* b_ih0 = (const float*)d_in[3];
  const float* b_hh0 = (const float*)d_in[4];
  const float* W_ih1 = (const float*)d_in[5];
  const float* W_hh1 = (const float*)d_in[6];
  const float* b_ih1 = (const float*)d_in[7];
  const float* b_hh1 = (const float*)d_in[8];
  const float* Wl    = (const float*)d_in[9];
  const float* bl    = (const float*)d_in[10];
  float* out = (float*)d_out;

  float* ws       = (float*)d_ws;
  float* xT       = ws;                         // 512*128*64
  float* h0ring   = xT + (size_t)TT * II * BB;  // 2*512*64
  float* h1ring   = h0ring + 2 * HH * BB;       // 2*512*64
  unsigned* flags = (unsigned*)(h1ring + 2 * HH * BB);  // 256 u32

  k_transpose_x<<<1024, 1024, 0, stream>>>(x, xT);
  k_init_flags<<<1, NBLK, 0, stream>>>(flags);

  hipFuncSetAttribute((const void*)k_lstm_persist,
                      hipFuncAttributeMaxDynamicSharedMemorySize, SMEM_BYTES);

  void* args[] = {
    (void*)&xT,
    (void*)&W_ih0, (void*)&W_hh0, (void*)&b_ih0, (void*)&b_hh0,
    (void*)&W_ih1, (void*)&W_hh1, (void*)&b_ih1, (void*)&b_hh1,
    (void*)&h0ring, (void*)&h1ring, (void*)&flags,
  };
  // Cooperative launch kept ONLY for the co-residency guarantee; sync is ours.
  hipLaunchCooperativeKernel((void*)k_lstm_persist, dim3(NBLK), dim3(1024),
                             args, SMEM_BYTES, stream);

  // h1[T-1] lives at ring parity (T-1)&1 == 1
  k_final<<<1, 512, 0, stream>>>(h1ring + HH * BB, Wl, bl, out);
}

// Round 13
// 7519.983 us; speedup vs baseline: 1.7641x; 1.7641x over previous
//
#include <hip/hip_runtime.h>
#include <cmath>

#define TT 512
#define BB 64
#define HH 512
#define II 128
#define NBLK 256

typedef float v2f __attribute__((ext_vector_type(2)));
__device__ __forceinline__ v2f fma2(v2f a, v2f b, v2f c) { return __builtin_elementwise_fma(a, b, c); }

// dynamic LDS floats: wlds 16*1024 =16384 | part 16*16*64 =16384 |
// gates 16*64 =1024 | cst 256 | bsum 16   => ~133 KB  (=> 1 block/CU)
#define SMEM_FLOATS (16384 + 16384 + 1024 + 256 + 16)
#define SMEM_BYTES  (SMEM_FLOATS * 4)

__device__ __forceinline__ float sigm(float v) { return 1.0f / (1.0f + expf(-v)); }
__device__ __forceinline__ unsigned umin2(unsigned a, unsigned b) { return a < b ? a : b; }
#define CBAR() asm volatile("" ::: "memory")   // compiler-only reorder fence

// One k-slice: 16 weights (rows 0..15) from LDS (wave-uniform broadcast),
// 8 v_pk_fma_f32. acc[j] covers rows (2j, 2j+1).
__device__ __forceinline__ void step(const float* wk, float v, v2f (&acc)[8]) {
  const float4* wp = (const float4*)wk;
  const float4 w0 = wp[0], w1 = wp[1], w2 = wp[2], w3 = wp[3];
  const v2f vb = (v2f){v, v};
  acc[0] = fma2((v2f){w0.x, w0.y}, vb, acc[0]);
  acc[1] = fma2((v2f){w0.z, w0.w}, vb, acc[1]);
  acc[2] = fma2((v2f){w1.x, w1.y}, vb, acc[2]);
  acc[3] = fma2((v2f){w1.z, w1.w}, vb, acc[3]);
  acc[4] = fma2((v2f){w2.x, w2.y}, vb, acc[4]);
  acc[5] = fma2((v2f){w2.z, w2.w}, vb, acc[5]);
  acc[6] = fma2((v2f){w3.x, w3.y}, vb, acc[6]);
  acc[7] = fma2((v2f){w3.z, w3.w}, vb, acc[7]);
}

// Bypass (relaxed AGENT atomic) batch loads: served from the coherence point,
// immune to stale local lines; compiler-managed waits (sound under spilling).
template<int KN>
__device__ __forceinline__ void loadva(const float* __restrict__ src, int k0,
                                       int b, float (&v)[KN]) {
#pragma unroll
  for (int i = 0; i < KN; ++i)
    v[i] = __hip_atomic_load(src + (size_t)(k0 + i) * BB + b,
                             __ATOMIC_RELAXED, __HIP_MEMORY_SCOPE_AGENT);
}
// Plain cached batch load (x only — immutable, stays L2-resident: no invs!).
template<int KN>
__device__ __forceinline__ void loadv(const float* __restrict__ src, int k0,
                                      int b, float (&v)[KN]) {
#pragma unroll
  for (int i = 0; i < KN; ++i) v[i] = src[(size_t)(k0 + i) * BB + b];
}
template<int KN>
__device__ __forceinline__ void consume(const float* __restrict__ wbase, int k0,
                                        const float (&v)[KN], v2f (&acc)[8]) {
#pragma unroll
  for (int i = 0; i < KN; ++i) step(wbase + (size_t)(k0 + i) * 16, v[i], acc);
}

// 32-k span, 8-deep ping-pong (<=16 staging floats live -> no spills at 64
// VGPR). Loads of batch n+1 overlap consumption of batch n; 4 waves/SIMD TLP
// covers the rest of the MALL latency.
__device__ __forceinline__ void span32(const float* __restrict__ src,
                                       const float* __restrict__ wbase,
                                       int k0, int b, v2f (&acc)[8]) {
  float va[8], vb_[8];
  loadva<8>(src, k0, b, va);
  loadva<8>(src, k0 + 8, b, vb_);
  consume<8>(wbase, k0, va, acc);
  loadva<8>(src, k0 + 16, b, va);
  consume<8>(wbase, k0 + 8, vb_, acc);
  loadva<8>(src, k0 + 24, b, vb_);
  consume<8>(wbase, k0 + 16, va, acc);
  consume<8>(wbase, k0 + 24, vb_, acc);
}

// ---------------------------------------------------------------------------
// Transpose x: [64][512][128] (b,t,k) -> xT: [512][128][64] (t,k,b)
// ---------------------------------------------------------------------------
__global__ __launch_bounds__(1024) void k_transpose_x(const float* __restrict__ x,
                                                      float* __restrict__ xT) {
  __shared__ float tile[64][65];
  const int t  = blockIdx.x >> 1;
  const int k0 = (blockIdx.x & 1) << 6;
  const int lk = threadIdx.x & 63;
  const int lb = threadIdx.x >> 6;
#pragma unroll
  for (int bp = 0; bp < 64; bp += 16) {
    const int b = bp + lb;
    tile[lk][b] = x[((size_t)b * TT + t) * II + k0 + lk];
  }
  __syncthreads();
  const int b2  = threadIdx.x & 63;
  const int kk0 = threadIdx.x >> 6;
#pragma unroll
  for (int kp = 0; kp < 64; kp += 16) {
    const int kk = kp + kk0;
    xT[((size_t)t * II + k0 + kk) * BB + b2] = tile[kk][b2];
  }
}

__global__ void k_init_flags(unsigned* flags) { flags[threadIdx.x] = 0u; }

// ---------------------------------------------------------------------------
// Persistent pipelined 2-layer LSTM — ZERO fences, zero cache maintenance.
// PRODUCER: h published via atomic EXCHANGE (swap-with-return, agent scope).
//   The return value exists only once the op performed at the MALL; the asm
//   sink forces s_waitcnt on the returns -> __syncthreads -> flag store is
//   ISSUED strictly after h is at the coherence point. Ordering by
//   construction, no __threadfence (the per-phase wbl2+inv storm was the
//   ~20us/phase cost in rounds 2/3/10/11).
// CONSUMER: round-12-PROVEN bypass atomic loads (read at MALL; no stale-line
//   exposure; depth-2 ring fine). x stays plain-cached (L2-resident now that
//   nothing invalidates L2).
// Staging is 8-deep ping-pong: <=16 floats live -> fits the 64-VGPR budget
//   the allocator enforces (round 11/12's 32-deep arrays spilled: 1.2-12 GB
//   of scratch traffic).
// Thread map: tid = kseg(4b) | b(6b); each thread: all 16 rows, K/16 k's.
// ---------------------------------------------------------------------------
__global__ __launch_bounds__(1024, 4) void k_lstm_persist(
    const float* __restrict__ xT,
    const float* __restrict__ W_ih0, const float* __restrict__ W_hh0,
    const float* __restrict__ b_ih0, const float* __restrict__ b_hh0,
    const float* __restrict__ W_ih1, const float* __restrict__ W_hh1,
    const float* __restrict__ b_ih1, const float* __restrict__ b_hh1,
    float* __restrict__ h0ring, float* __restrict__ h1ring,
    unsigned* __restrict__ flags)
{
  extern __shared__ float smem[];
  float* wlds  = smem;            // [k up to 1024][16 rows] k-major
  float* part  = wlds + 16384;    // [row16][kseg16][b64]
  float* gates = part + 16384;    // [row16][b64]
  float* cst   = gates + 1024;    // [u4][b64]
  float* bsum  = cst + 256;       // [16]

  const int bid = blockIdx.x;
  const int L   = bid >> 7;
  const int ub  = (bid & 127) << 2;   // 4 hidden units per block
  const int tid = threadIdx.x;

  const float* WA = L ? W_ih1 : W_ih0;
  const float* WB = L ? W_hh1 : W_hh0;
  const int KA = L ? HH : II;

  // ---- one-time: stage weights k-major + bias sums + c=0 ----
  const int ktot = KA + HH;
  for (int idx = tid; idx < 16 * ktot; idx += 1024) {
    const int k  = idx >> 4;
    const int lr = idx & 15;
    const int u = lr >> 2, q = lr & 3;
    const int G = q * HH + ub + u;           // i,f,g,o chunk order
    wlds[idx] = (k < KA) ? WA[G * KA + k] : WB[G * HH + (k - KA)];
  }
  if (tid < 16) {
    const int u = tid >> 2, q = tid & 3;
    const int G = q * HH + ub + u;
    bsum[tid] = L ? (b_ih1[G] + b_hh1[G]) : (b_ih0[G] + b_hh0[G]);
  }
  if (tid < 256) cst[tid] = 0.0f;
  __syncthreads();

  const int kseg = tid >> 6;   // 0..15
  const int b    = tid & 63;

  for (int s = 0; s <= TT; ++s) {
    const int t = L ? (s - 1) : s;
    const bool active = (t >= 0 && t < TT);
    const bool first  = (t == 0);

    v2f acc[8];
#pragma unroll
    for (int j = 0; j < 8; ++j) acc[j] = (v2f){0.0f, 0.0f};

    // ---- L0 x loads BEFORE the wait (immutable; complete during spin) ----
    float xv[8];
    if (active && L == 0) {
      loadv<8>(xT + (size_t)t * (II * BB), kseg * 8, b, xv);
    }

    // ---- wait: all blocks published phase s-1 (no fence needed) ----
    if (s > 0) {
      if (tid < 64) {
        const unsigned tgt = (unsigned)s;
        for (;;) {
          const unsigned m0 = __hip_atomic_load(flags + tid,       __ATOMIC_RELAXED, __HIP_MEMORY_SCOPE_AGENT);
          const unsigned m1 = __hip_atomic_load(flags + tid +  64, __ATOMIC_RELAXED, __HIP_MEMORY_SCOPE_AGENT);
          const unsigned m2 = __hip_atomic_load(flags + tid + 128, __ATOMIC_RELAXED, __HIP_MEMORY_SCOPE_AGENT);
          const unsigned m3 = __hip_atomic_load(flags + tid + 192, __ATOMIC_RELAXED, __HIP_MEMORY_SCOPE_AGENT);
          const unsigned mn = umin2(umin2(m0, m1), umin2(m2, m3));
          if (__all(mn >= tgt)) break;
          __builtin_amdgcn_s_sleep(1);
        }
      }
      __syncthreads();
      CBAR();   // keep h loads below the spin at IR level
    }

    if (active) {
      if (L == 0) {
        consume<8>(wlds, kseg * 8, xv, acc);
        if (!first) {  // B-part: h0[s-1] @ parity (s-1)&1
          span32(h0ring + (size_t)((s - 1) & 1) * (HH * BB),
                 wlds + (size_t)II * 16, kseg * 32, b, acc);
        }
      } else {
        const float* h0p = h0ring + (size_t)((s - 1) & 1) * (HH * BB);
        span32(h0p, wlds, kseg * 32, b, acc);
        if (!first) {  // B-part: h1[s-2] @ parity s&1
          span32(h1ring + (size_t)(s & 1) * (HH * BB),
                 wlds + (size_t)HH * 16, kseg * 32, b, acc);
        }
      }

      // ---- reduce 16 ksegs -> gates (lanes = b: conflict-free) ----
#pragma unroll
      for (int j = 0; j < 4; ++j) {
        part[(((j << 2) + 0) * 16 + kseg) * 64 + b] = acc[(j << 1)].x;
        part[(((j << 2) + 1) * 16 + kseg) * 64 + b] = acc[(j << 1)].y;
        part[(((j << 2) + 2) * 16 + kseg) * 64 + b] = acc[(j << 1) + 1].x;
        part[(((j << 2) + 3) * 16 + kseg) * 64 + b] = acc[(j << 1) + 1].y;
      }
      __syncthreads();
      {
        const int row = tid >> 6;
        const int bb  = tid & 63;
        float g = 0.0f;
#pragma unroll
        for (int ks = 0; ks < 16; ++ks) g += part[(row * 16 + ks) * 64 + bb];
        gates[row * 64 + bb] = g + bsum[row];
      }
      __syncthreads();

      if (tid < 256) {  // cell update; h published via swap-with-return
        const int u = tid >> 6, bb = tid & 63;
        const float gi = sigm(gates[((u << 2) + 0) * 64 + bb]);
        const float gf = sigm(gates[((u << 2) + 1) * 64 + bb]);
        const float gg = tanhf(gates[((u << 2) + 2) * 64 + bb]);
        const float go = sigm(gates[((u << 2) + 3) * 64 + bb]);
        const float cold = first ? 0.0f : cst[u * 64 + bb];
        const float cn = gf * cold + gi * gg;
        const float hn = go * tanhf(cn);
        cst[u * 64 + bb] = cn;
        float* hdst = (L ? h1ring : h0ring) + (size_t)(t & 1) * (HH * BB);
        // swap-with-return: the returned value proves the op performed at the
        // MALL; the asm sink forces the s_waitcnt on it HERE (before barrier).
        float old = __hip_atomic_exchange(hdst + (ub + u) * 64 + bb, hn,
                                          __ATOMIC_RELAXED, __HIP_MEMORY_SCOPE_AGENT);
        asm volatile("" :: "v"(old));
      }
    }

    // all swaps' returns received (h at MALL) before any thread passes here;
    // the flag store is issued strictly afterwards -> cannot be seen early.
    __syncthreads();
    if (tid == 0) {
      __hip_atomic_store(flags + bid, (unsigned)(s + 1),
                         __ATOMIC_RELAXED, __HIP_MEMORY_SCOPE_AGENT);
    }
  }
}

// ---------------------------------------------------------------------------
// out[b] = sum_j h1_last[j][b] * Wl[j] + bl[0]
// ---------------------------------------------------------------------------
__global__ __launch_bounds__(512) void k_final(const float* __restrict__ h1last,
                                               const float* __restrict__ Wl,
                                               const float* __restrict__ bl,
                                               float* __restrict__ out) {
  __shared__ float red[8][64];
  const int jg = threadIdx.x >> 6, b = threadIdx.x & 63;
  float a = 0.0f;
  for (int jj = 0; jj < 64; ++jj) {
    const int j = (jg << 6) + jj;
    a += h1last[j * BB + b] * Wl[j];
  }
  red[jg][b] = a;
  __syncthreads();
  if (threadIdx.x < 64) {
    float s = bl[0];
#pragma unroll
    for (int g = 0; g < 8; ++g) s += red[g][threadIdx.x];
    out[threadIdx.x] = s;
  }
}

extern "C" void kernel_launch(void* const* d_in, const int* in_sizes, int n_in,
                              void* d_out, int out_size, void* d_ws, size_t ws_size,
                              hipStream_t stream) {
  (void)in_sizes; (void)n_in; (void)out_size; (void)ws_size;
  const float* x     = (const float*)d_in[0];
  const float* W_ih0 = (const float*)d_in[1];
  const float* W_hh0 = (const float*)d_in[2];
  const float* b_ih0 = (const float*)d_in[3];
  const float* b_hh0 = (const float*)d_in[4];
  const float* W_ih1 = (const float*)d_in[5];
  const float* W_hh1 = (const float*)d_in[6];
  const float* b_ih1 = (const float*)d_in[7];
  const float* b_hh1 = (const float*)d_in[8];
  const float* Wl    = (const float*)d_in[9];
  const float* bl    = (const float*)d_in[10];
  float* out = (float*)d_out;

  float* ws       = (float*)d_ws;
  float* xT       = ws;                         // 512*128*64
  float* h0ring   = xT + (size_t)TT * II * BB;  // 2*512*64
  float* h1ring   = h0ring + 2 * HH * BB;       // 2*512*64
  unsigned* flags = (unsigned*)(h1ring + 2 * HH * BB);  // 256 u32

  k_transpose_x<<<1024, 1024, 0, stream>>>(x, xT);
  k_init_flags<<<1, NBLK, 0, stream>>>(flags);

  hipFuncSetAttribute((const void*)k_lstm_persist,
                      hipFuncAttributeMaxDynamicSharedMemorySize, SMEM_BYTES);

  void* args[] = {
    (void*)&xT,
    (void*)&W_ih0, (void*)&W_hh0, (void*)&b_ih0, (void*)&b_hh0,
    (void*)&W_ih1, (void*)&W_hh1, (void*)&b_ih1, (void*)&b_hh1,
    (void*)&h0ring, (void*)&h1ring, (void*)&flags,
  };
  // Cooperative launch kept ONLY for the co-residency guarantee; sync is ours.
  hipLaunchCooperativeKernel((void*)k_lstm_persist, dim3(NBLK), dim3(1024),
                             args, SMEM_BYTES, stream);

  // h1[T-1] lives at ring parity (T-1)&1 == 1
  k_final<<<1, 512, 0, stream>>>(h1ring + HH * BB, Wl, bl, out);
}